// Round 14
// baseline (201.060 us; speedup 1.0000x reference)
//
#include <hip/hip_runtime.h>
#include <cfloat>

#define BB 32
#define NN 2048
#define DD 128
#define RM 128    // rows per block (4 waves x 32 rows/wave)
#define CN 64     // cols per tile
#define NT (NN / CN)

typedef __attribute__((ext_vector_type(8))) short short8;
typedef __attribute__((ext_vector_type(4))) short short4v;
typedef __attribute__((ext_vector_type(4))) float float4v;

__device__ __forceinline__ unsigned short f2bf(float f) {
    unsigned int u = __builtin_bit_cast(unsigned int, f);
    u += 0x7FFFu + ((u >> 16) & 1u);   // RNE
    return (unsigned short)(u >> 16);
}

__device__ __forceinline__ unsigned int umn(unsigned int a, unsigned int b) { return a < b ? a : b; }
__device__ __forceinline__ unsigned int umx(unsigned int a, unsigned int b) { return a > b ? a : b; }
#define CSU(a, b) { unsigned int _lo = umn(a, b), _hi = umx(a, b); (a) = _lo; (b) = _hi; }

// median-of-3 (u32): sorted-insert primitive (1 VOP3 inst).
__device__ __forceinline__ unsigned int umed3(unsigned int a, unsigned int b, unsigned int c) {
    unsigned int d;
    asm("v_med3_u32 %0, %1, %2, %3" : "=v"(d) : "v"(a), "v"(b), "v"(c));
    return d;
}

// async global->LDS, 16B per lane. LDS dest is wave-uniform base + lane*16.
__device__ __forceinline__ void gl2lds16(const unsigned short* g, unsigned short* l) {
    __builtin_amdgcn_global_load_lds(
        (const __attribute__((address_space(1))) void*)g,
        (__attribute__((address_space(3))) void*)l, 16, 0, 0);
}

// fused: sq = sum(x^2) per row, and bf16 copy of x into workspace.
// Fully coalesced: thread t owns 16-B chunk t; 32 chunks/row -> shfl_xor reduce.
__global__ __launch_bounds__(256) void prep_kernel(const float* __restrict__ x,
        unsigned short* __restrict__ xb16, float* __restrict__ sq) {
    int c = blockIdx.x * 256 + threadIdx.x;          // chunk id, 4 floats each
    float4 v = *reinterpret_cast<const float4*>(x + (size_t)c * 4);
    short4v pk;
    pk[0] = (short)f2bf(v.x); pk[1] = (short)f2bf(v.y);
    pk[2] = (short)f2bf(v.z); pk[3] = (short)f2bf(v.w);
    *reinterpret_cast<short4v*>(xb16 + (size_t)c * 4) = pk;
    float acc = v.x * v.x + v.y * v.y + v.z * v.z + v.w * v.w;
    acc += __shfl_xor(acc, 1);
    acc += __shfl_xor(acc, 2);
    acc += __shfl_xor(acc, 4);
    acc += __shfl_xor(acc, 8);
    acc += __shfl_xor(acc, 16);
    if ((threadIdx.x & 31) == 0) sq[c >> 5] = acc;   // 32 chunks (128 floats) per row
}

__global__ __launch_bounds__(256) void sq_kernel(const float* __restrict__ x,
                                                 float* __restrict__ sq) {
    int t = blockIdx.x * 256 + threadIdx.x;
    int row = t >> 2;
    int q = t & 3;
    const float4* xp = reinterpret_cast<const float4*>(x + (size_t)row * DD + q * 32);
    float acc = 0.f;
#pragma unroll
    for (int i = 0; i < 8; ++i) {
        float4 v = xp[i];
        acc += v.x * v.x + v.y * v.y + v.z * v.z + v.w * v.w;
    }
    acc += __shfl_xor(acc, 1);
    acc += __shfl_xor(acc, 2);
    if (q == 0) sq[row] = acc;
}

// B tile layout (per buffer): row r (0..63), 16 chunks of 8 bf16; chunk c at pos c^(r&7).
// Base = verified R12 (triple-buffer, counted vmcnt(4), raw barrier, 119.7 us).
// NEW (T15 defer-selection): tile ct's MFMAs accumulate into acc{ct&1} (two NAMED
// arrays, static indexing); the VALU-heavy selection for tile ct-1 is issued in the
// same step from the OTHER parity's acc+sqb, overlapping the current tile's MFMA
// pipe (MFMA and VALU are separate pipes). One epilogue selection after the loop.
template<bool PRE>
__global__ __launch_bounds__(256, 2) void knn_kernel(const float* __restrict__ x,
        const unsigned short* __restrict__ xb16g,
        const float* __restrict__ sqv, const float* __restrict__ strength,
        float* __restrict__ out) {
    __shared__ __align__(16) unsigned short btile[3 * CN * DD]; // 48 KB, triple-buffered
    __shared__ unsigned int cand8[RM * 8];                      // 4 KB => 52 KB => 2 blocks/CU

    const int b = blockIdx.x;            // all 16 row-blocks of a batch share an XCD
    const int row0 = blockIdx.y * RM;
    const int tid = threadIdx.x;
    const int w = tid >> 6;
    const int lane = tid & 63;
    const int m = lane & 15;
    const int quad = lane >> 4;
    const float* __restrict__ xb = x + (size_t)b * NN * DD;
    const unsigned short* __restrict__ gb = PRE ? xb16g + (size_t)b * NN * DD : nullptr;

    // ---- A fragments direct from global: 2 row-groups x 4 k-chunks per lane ----
    short8 afrag[2][4];
    if constexpr (PRE) {
#pragma unroll
        for (int rg = 0; rg < 2; ++rg)
#pragma unroll
            for (int kc = 0; kc < 4; ++kc)
                afrag[rg][kc] = *reinterpret_cast<const short8*>(
                    gb + (size_t)(row0 + 32 * w + rg * 16 + m) * DD + kc * 32 + quad * 8);
    } else {
#pragma unroll
        for (int rg = 0; rg < 2; ++rg)
#pragma unroll
            for (int kc = 0; kc < 4; ++kc) {
                const float4* src = reinterpret_cast<const float4*>(
                    xb + (size_t)(row0 + 32 * w + rg * 16 + m) * DD + kc * 32 + quad * 8);
                float4 v0 = src[0], v1 = src[1];
                short8 pk;
                pk[0] = (short)f2bf(v0.x); pk[1] = (short)f2bf(v0.y);
                pk[2] = (short)f2bf(v0.z); pk[3] = (short)f2bf(v0.w);
                pk[4] = (short)f2bf(v1.x); pk[5] = (short)f2bf(v1.y);
                pk[6] = (short)f2bf(v1.z); pk[7] = (short)f2bf(v1.w);
                afrag[rg][kc] = pk;
            }
    }

    unsigned short* cur = btile;
    unsigned short* n1  = btile + CN * DD;
    unsigned short* n2  = btile + 2 * CN * DD;

    // ---- prologue: stage tiles 0 and 1; sq for tile 0; full drain once ----
    if constexpr (PRE) {
#pragma unroll
        for (int l = 0; l < 4; ++l) {
            int f = (l * 4 + w) * 64 + lane;
            int r = f >> 4, p = f & 15;
            int c = p ^ (r & 7);
            gl2lds16(gb + (size_t)r * DD + c * 8, cur + (l * 4 + w) * 512);
        }
#pragma unroll
        for (int l = 0; l < 4; ++l) {
            int f = (l * 4 + w) * 64 + lane;
            int r = f >> 4, p = f & 15;
            int c = p ^ (r & 7);
            gl2lds16(gb + (size_t)(CN + r) * DD + c * 8, n1 + (l * 4 + w) * 512);
        }
    } else {
#pragma unroll
        for (int l = 0; l < 8; ++l) {
            int id = l * 256 + tid;                 // tiles 0 and 1 = rows 0..127
            int r = id >> 4, c = id & 15, p = c ^ (r & 7);
            const float4* src = reinterpret_cast<const float4*>(xb + (size_t)r * DD + c * 8);
            float4 v0 = src[0], v1 = src[1];
            short8 pk;
            pk[0] = (short)f2bf(v0.x); pk[1] = (short)f2bf(v0.y);
            pk[2] = (short)f2bf(v0.z); pk[3] = (short)f2bf(v0.w);
            pk[4] = (short)f2bf(v1.x); pk[5] = (short)f2bf(v1.y);
            pk[6] = (short)f2bf(v1.z); pk[7] = (short)f2bf(v1.w);
            *reinterpret_cast<short8*>(btile + r * DD + p * 8) = pk;  // cur|n1 contiguous
        }
    }
    float sqb0[4], sqb1[4];
#pragma unroll
    for (int cc = 0; cc < 4; ++cc)
        sqb0[cc] = sqv[(size_t)b * NN + cc * 16 + m] + 1024.0f;   // sq(tile 0)
    __syncthreads();   // one-time full drain: tiles 0,1 + sq ready

    // per-(lane, rg, reg) sorted top-4 packed keys (ascending).
    // Lossless: only 3 keys can be globally smaller than true rank-3, so it
    // can never be evicted from its lane-class top-4.
    unsigned int tk[2][4][4];
#pragma unroll
    for (int rg = 0; rg < 2; ++rg)
#pragma unroll
        for (int i = 0; i < 4; ++i)
#pragma unroll
            for (int q = 0; q < 4; ++q) tk[rg][i][q] = 0xFFFFFFFFu;

    float4v acc0[2][4], acc1[2][4];

// Selection for pending tile CTP from ACCP/SQBP (pure-register; overlaps MFMA pipe).
#define SEL(ACCP, SQBP, CTP)                                                           \
    {                                                                                  \
        _Pragma("unroll")                                                              \
        for (int cc = 0; cc < 4; ++cc) {                                               \
            unsigned int col = (unsigned int)((CTP) * CN + cc * 16 + m);               \
            _Pragma("unroll")                                                          \
            for (int rg = 0; rg < 2; ++rg)                                             \
                _Pragma("unroll")                                                      \
                for (int reg = 0; reg < 4; ++reg) {                                    \
                    float scb = fmaf(-2.f, ACCP[rg][cc][reg], SQBP[cc]);               \
                    unsigned int key =                                                 \
                        (__builtin_bit_cast(unsigned int, scb) & 0xFFFFF800u) | col;   \
                    unsigned int t0 = tk[rg][reg][0], t1 = tk[rg][reg][1];             \
                    unsigned int t2 = tk[rg][reg][2], t3 = tk[rg][reg][3];             \
                    tk[rg][reg][0] = umn(t0, key);                                     \
                    tk[rg][reg][1] = umed3(t0, t1, key);                               \
                    tk[rg][reg][2] = umed3(t1, t2, key);                               \
                    tk[rg][reg][3] = umed3(t2, t3, key);                               \
                }                                                                      \
        }                                                                              \
    }

// One tile step. ACC_CUR receives tile CT's MFMAs; ACC_PEN/SQB_PEN are tile CT-1's
// (selected here when DOSEL). SQB_PEN is then re-filled with sq(CT+1) — same parity.
#define STEP(ACC_CUR, ACC_PEN, SQB_PEN, CT, DOSEL)                                     \
    {                                                                                  \
        const int ct = (CT);                                                           \
        /* 1. prefetch sq for tile ct+1 (issued BEFORE the stage ops) */               \
        float sqn[4];                                                                  \
        if (ct + 1 < NT) {                                                             \
            _Pragma("unroll")                                                          \
            for (int cc = 0; cc < 4; ++cc)                                             \
                sqn[cc] = sqv[(size_t)b * NN + (ct + 1) * CN + cc * 16 + m];           \
        }                                                                              \
        asm volatile("" ::: "memory");   /* pin order: sqv loads precede stage */      \
        /* 2. stage tile ct+2 into n2 (stays in flight across the barrier) */          \
        if (ct + 2 < NT) {                                                             \
            int cb = (ct + 2) * CN;                                                    \
            if constexpr (PRE) {                                                       \
                _Pragma("unroll")                                                      \
                for (int l = 0; l < 4; ++l) {                                          \
                    int f = (l * 4 + w) * 64 + lane;                                   \
                    int r = f >> 4, p = f & 15;                                        \
                    int c = p ^ (r & 7);                                               \
                    gl2lds16(gb + (size_t)(cb + r) * DD + c * 8,                       \
                             n2 + (l * 4 + w) * 512);                                  \
                }                                                                      \
            } else {                                                                   \
                _Pragma("unroll")                                                      \
                for (int l = 0; l < 4; ++l) {                                          \
                    int id = l * 256 + tid;                                            \
                    int r = id >> 4, c = id & 15, p = c ^ (r & 7);                     \
                    const float4* src = reinterpret_cast<const float4*>(               \
                        xb + (size_t)(cb + r) * DD + c * 8);                           \
                    float4 v0 = src[0], v1 = src[1];                                   \
                    short8 pk;                                                         \
                    pk[0] = (short)f2bf(v0.x); pk[1] = (short)f2bf(v0.y);              \
                    pk[2] = (short)f2bf(v0.z); pk[3] = (short)f2bf(v0.w);              \
                    pk[4] = (short)f2bf(v1.x); pk[5] = (short)f2bf(v1.y);              \
                    pk[6] = (short)f2bf(v1.z); pk[7] = (short)f2bf(v1.w);              \
                    *reinterpret_cast<short8*>(n2 + r * DD + p * 8) = pk;              \
                }                                                                      \
            }                                                                          \
        }                                                                              \
        /* 3. MFMA tile ct -> ACC_CUR: 32 MFMAs from 16 b128 reads (reuse=2) */        \
        _Pragma("unroll")                                                              \
        for (int rg = 0; rg < 2; ++rg)                                                 \
            _Pragma("unroll")                                                          \
            for (int cc = 0; cc < 4; ++cc)                                             \
                ACC_CUR[rg][cc] = (float4v){0.f, 0.f, 0.f, 0.f};                       \
        _Pragma("unroll")                                                              \
        for (int kc = 0; kc < 4; ++kc) {                                               \
            short8 bfrag[4];                                                           \
            _Pragma("unroll")                                                          \
            for (int cc = 0; cc < 4; ++cc) {                                           \
                int rl = cc * 16 + m;                                                  \
                int p = (kc * 4 + quad) ^ (m & 7);                                     \
                bfrag[cc] = *reinterpret_cast<const short8*>(cur + rl * DD + p * 8);   \
            }                                                                          \
            _Pragma("unroll")                                                          \
            for (int rg = 0; rg < 2; ++rg)                                             \
                _Pragma("unroll")                                                      \
                for (int cc = 0; cc < 4; ++cc)                                         \
                    ACC_CUR[rg][cc] = __builtin_amdgcn_mfma_f32_16x16x32_bf16(         \
                        afrag[rg][kc], bfrag[cc], ACC_CUR[rg][cc], 0, 0, 0);           \
        }                                                                              \
        /* 4. deferred selection for tile ct-1 (independent of step-3 MFMAs) */        \
        if (DOSEL) SEL(ACC_PEN, SQB_PEN, ct - 1)                                       \
        /* 5. roll sq: SQB_PEN <- sq(ct+1) (same parity as ct-1) */                    \
        if (ct + 1 < NT) {                                                             \
            _Pragma("unroll")                                                          \
            for (int cc = 0; cc < 4; ++cc) SQB_PEN[cc] = sqn[cc] + 1024.0f;            \
        }                                                                              \
        /* 6. counted wait + barrier (identical to verified R12) */                    \
        if constexpr (PRE) {                                                           \
            if (ct + 2 < NT) {                                                         \
                asm volatile("s_waitcnt vmcnt(4)" ::: "memory");                       \
            } else {                                                                   \
                asm volatile("s_waitcnt vmcnt(0)" ::: "memory");                       \
            }                                                                          \
            __builtin_amdgcn_s_barrier();                                              \
            __builtin_amdgcn_sched_barrier(0);                                         \
        } else {                                                                       \
            __syncthreads();                                                           \
        }                                                                              \
        /* 7. rotate buffers */                                                        \
        unsigned short* t = cur; cur = n1; n1 = n2; n2 = t;                            \
    }

#pragma unroll 1
    for (int ct2 = 0; ct2 < NT; ct2 += 2) {
        STEP(acc0, acc1, sqb1, ct2, (ct2 > 0))      // even tile -> acc0; select odd pending
        STEP(acc1, acc0, sqb0, ct2 + 1, true)       // odd tile -> acc1; select even pending
    }
    // epilogue: select the last tile (NT-1 odd -> acc1; sqb1 = sq(NT-1))
    SEL(acc1, sqb1, NT - 1)
#undef STEP
#undef SEL

    // ---- in-register merge: 16 lanes/quad-group x sorted-4 -> row top-8 ----
#pragma unroll
    for (int rg = 0; rg < 2; ++rg)
#pragma unroll
        for (int reg = 0; reg < 4; ++reg) {
            unsigned int e[8];
#pragma unroll
            for (int j = 0; j < 4; ++j) e[j] = tk[rg][reg][j];
#pragma unroll
            for (int j = 4; j < 8; ++j) e[j] = 0xFFFFFFFFu;
#pragma unroll
            for (int st = 0; st < 4; ++st) {
                int mask = 1 << st;
                unsigned int rv[8];
#pragma unroll
                for (int j = 0; j < 8; ++j)
                    rv[j] = (unsigned int)__shfl_xor((int)e[7 - j], mask, 64);
#pragma unroll
                for (int j = 0; j < 8; ++j) e[j] = umn(e[j], rv[j]);
                CSU(e[0], e[4]); CSU(e[1], e[5]); CSU(e[2], e[6]); CSU(e[3], e[7]);
                CSU(e[0], e[2]); CSU(e[1], e[3]); CSU(e[4], e[6]); CSU(e[5], e[7]);
                CSU(e[0], e[1]); CSU(e[2], e[3]); CSU(e[4], e[5]); CSU(e[6], e[7]);
            }
            if (m == 0) {
                int row = 32 * w + rg * 16 + quad * 4 + reg;
#pragma unroll
                for (int j = 0; j < 8; ++j) cand8[row * 8 + j] = e[j];
            }
        }
    __syncthreads();

    // alias btile for refine scratch (all tile reads done)
    double* refd = reinterpret_cast<double*>(btile);           // 8 KB
    int* best3 = reinterpret_cast<int*>(btile) + 2048;         // next 1.5 KB

    // ---- refine: exact fp64 distance; 2 threads/row x 4 candidates ----
    {
        int r = tid >> 1, h = tid & 1;
        int grow = row0 + r;
        int ci[4];
#pragma unroll
        for (int j = 0; j < 4; ++j) ci[j] = (int)(cand8[r * 8 + h * 4 + j] & 0x7FFu);
        const float* pr = xb + (size_t)grow * DD;
        const float* pc[4];
#pragma unroll
        for (int j = 0; j < 4; ++j) pc[j] = xb + (size_t)ci[j] * DD;
        double a[4] = {0.0, 0.0, 0.0, 0.0};
#pragma unroll 4
        for (int d4 = 0; d4 < 32; ++d4) {
            float4 wv = *reinterpret_cast<const float4*>(pr + d4 * 4);
#pragma unroll
            for (int j = 0; j < 4; ++j) {
                float4 v = *reinterpret_cast<const float4*>(pc[j] + d4 * 4);
                double d;
                d = (double)wv.x - (double)v.x; a[j] += d * d;
                d = (double)wv.y - (double)v.y; a[j] += d * d;
                d = (double)wv.z - (double)v.z; a[j] += d * d;
                d = (double)wv.w - (double)v.w; a[j] += d * d;
            }
        }
#pragma unroll
        for (int j = 0; j < 4; ++j)
            refd[r * 8 + h * 4 + j] = (ci[j] == grow) ? DBL_MAX : a[j];
    }
    __syncthreads();

    // ---- final top-3 by (exact d2, idx) ----
    if (tid < RM) {
        int r = tid;
        double b0 = DBL_MAX, b1 = DBL_MAX, b2 = DBL_MAX;
        int i0 = 0x7fffffff, i1 = 0x7fffffff, i2 = 0x7fffffff;
        for (int e = 0; e < 8; ++e) {
            double dv = refd[r * 8 + e];
            int ix = (int)(cand8[r * 8 + e] & 0x7FFu);
            if (dv < b2 || (dv == b2 && ix < i2)) {
                b2 = dv; i2 = ix;
                if (b1 > b2 || (b1 == b2 && i1 > i2)) { double td = b1; b1 = b2; b2 = td; int tn = i1; i1 = i2; i2 = tn; }
                if (b0 > b1 || (b0 == b1 && i0 > i1)) { double td = b0; b0 = b1; b1 = td; int tn = i0; i0 = i1; i1 = tn; }
            }
        }
        best3[r * 3 + 0] = i0; best3[r * 3 + 1] = i1; best3[r * 3 + 2] = i2;
    }
    __syncthreads();

    // ---- output: 2 threads/row x 64 floats ----
    {
        int r = tid >> 1, q = tid & 1;
        float s = fminf(fmaxf(strength[0], 0.f), 1.f);
        const float* pa = xb + (size_t)(row0 + r) * DD + q * 64;
        const float* p1 = xb + (size_t)best3[r * 3 + 0] * DD + q * 64;
        const float* p2 = xb + (size_t)best3[r * 3 + 1] * DD + q * 64;
        const float* p3 = xb + (size_t)best3[r * 3 + 2] * DD + q * 64;
        float* po = out + ((size_t)b * NN + row0 + r) * DD + q * 64;
#pragma unroll
        for (int l = 0; l < 16; ++l) {
            float4 a  = *reinterpret_cast<const float4*>(pa + l * 4);
            float4 v1 = *reinterpret_cast<const float4*>(p1 + l * 4);
            float4 v2 = *reinterpret_cast<const float4*>(p2 + l * 4);
            float4 v3 = *reinterpret_cast<const float4*>(p3 + l * 4);
            float4 o;
            o.x = (1.f - s) * a.x + s * ((v1.x + v2.x + v3.x) / 3.f);
            o.y = (1.f - s) * a.y + s * ((v1.y + v2.y + v3.y) / 3.f);
            o.z = (1.f - s) * a.z + s * ((v1.z + v2.z + v3.z) / 3.f);
            o.w = (1.f - s) * a.w + s * ((v1.w + v2.w + v3.w) / 3.f);
            *reinterpret_cast<float4*>(po + l * 4) = o;
        }
    }
}

extern "C" void kernel_launch(void* const* d_in, const int* in_sizes, int n_in,
                              void* d_out, int out_size, void* d_ws, size_t ws_size,
                              hipStream_t stream) {
    const float* x = (const float*)d_in[0];
    const float* strength = (const float*)d_in[1];
    float* out = (float*)d_out;
    float* sq = (float*)d_ws;
    unsigned short* xb16 = (unsigned short*)((char*)d_ws + 256 * 1024);
    const size_t need = 256 * 1024 + (size_t)BB * NN * DD * sizeof(unsigned short);

    if (ws_size >= need) {
        prep_kernel<<<dim3((BB * NN * DD / 4) / 256), 256, 0, stream>>>(x, xb16, sq);
        knn_kernel<true><<<dim3(BB, NN / RM), 256, 0, stream>>>(x, xb16, sq, strength, out);
    } else {
        sq_kernel<<<dim3((BB * NN * 4) / 256), 256, 0, stream>>>(x, sq);
        knn_kernel<false><<<dim3(BB, NN / RM), 256, 0, stream>>>(x, nullptr, sq, strength, out);
    }
}

// Round 15
// 186.039 us; speedup vs baseline: 1.0807x; 1.0807x over previous
//
#include <hip/hip_runtime.h>
#include <cfloat>

#define BB 32
#define NN 2048
#define DD 128
#define RM 128    // rows per block (4 waves x 32 rows/wave)
#define CN 64     // cols per tile
#define NT (NN / CN)

typedef __attribute__((ext_vector_type(8))) short short8;
typedef __attribute__((ext_vector_type(4))) short short4v;
typedef __attribute__((ext_vector_type(4))) float float4v;

__device__ __forceinline__ unsigned short f2bf(float f) {
    unsigned int u = __builtin_bit_cast(unsigned int, f);
    u += 0x7FFFu + ((u >> 16) & 1u);   // RNE
    return (unsigned short)(u >> 16);
}

__device__ __forceinline__ unsigned int umn(unsigned int a, unsigned int b) { return a < b ? a : b; }
__device__ __forceinline__ unsigned int umx(unsigned int a, unsigned int b) { return a > b ? a : b; }
#define CSU(a, b) { unsigned int _lo = umn(a, b), _hi = umx(a, b); (a) = _lo; (b) = _hi; }

// median-of-3 (u32): sorted-insert primitive (1 VOP3 inst).
__device__ __forceinline__ unsigned int umed3(unsigned int a, unsigned int b, unsigned int c) {
    unsigned int d;
    asm("v_med3_u32 %0, %1, %2, %3" : "=v"(d) : "v"(a), "v"(b), "v"(c));
    return d;
}

// async global->LDS, 16B per lane. LDS dest is wave-uniform base + lane*16.
__device__ __forceinline__ void gl2lds16(const unsigned short* g, unsigned short* l) {
    __builtin_amdgcn_global_load_lds(
        (const __attribute__((address_space(1))) void*)g,
        (__attribute__((address_space(3))) void*)l, 16, 0, 0);
}

// fused: sq = sum(x^2) per row, and bf16 copy of x into workspace.
// Fully coalesced: thread t owns 16-B chunk t; 32 chunks/row -> shfl_xor reduce.
__global__ __launch_bounds__(256) void prep_kernel(const float* __restrict__ x,
        unsigned short* __restrict__ xb16, float* __restrict__ sq) {
    int c = blockIdx.x * 256 + threadIdx.x;          // chunk id, 4 floats each
    float4 v = *reinterpret_cast<const float4*>(x + (size_t)c * 4);
    short4v pk;
    pk[0] = (short)f2bf(v.x); pk[1] = (short)f2bf(v.y);
    pk[2] = (short)f2bf(v.z); pk[3] = (short)f2bf(v.w);
    *reinterpret_cast<short4v*>(xb16 + (size_t)c * 4) = pk;
    float acc = v.x * v.x + v.y * v.y + v.z * v.z + v.w * v.w;
    acc += __shfl_xor(acc, 1);
    acc += __shfl_xor(acc, 2);
    acc += __shfl_xor(acc, 4);
    acc += __shfl_xor(acc, 8);
    acc += __shfl_xor(acc, 16);
    if ((threadIdx.x & 31) == 0) sq[c >> 5] = acc;   // 32 chunks (128 floats) per row
}

__global__ __launch_bounds__(256) void sq_kernel(const float* __restrict__ x,
                                                 float* __restrict__ sq) {
    int t = blockIdx.x * 256 + threadIdx.x;
    int row = t >> 2;
    int q = t & 3;
    const float4* xp = reinterpret_cast<const float4*>(x + (size_t)row * DD + q * 32);
    float acc = 0.f;
#pragma unroll
    for (int i = 0; i < 8; ++i) {
        float4 v = xp[i];
        acc += v.x * v.x + v.y * v.y + v.z * v.z + v.w * v.w;
    }
    acc += __shfl_xor(acc, 1);
    acc += __shfl_xor(acc, 2);
    if (q == 0) sq[row] = acc;
}

// B tile layout (per buffer): row r (0..63), 16 chunks of 8 bf16; chunk c at pos c^(r&7).
// T4 pipeline (PRE path): 3 LDS buffers; stage tile ct+2 while computing ct; end each
// tile with counted s_waitcnt vmcnt(4) + raw s_barrier so stage(ct+2)'s 4 ops/thread
// stay in flight across the barrier (vs a full vmcnt(0) drain 32x per block).
// Issue order per iter is pinned (sqv prefetch -> fence -> stage) so FIFO vmcnt
// retirement makes vmcnt(4) retire exactly stage(ct+1) and older.
template<bool PRE>
__global__ __launch_bounds__(256, 2) void knn_kernel(const float* __restrict__ x,
        const unsigned short* __restrict__ xb16g,
        const float* __restrict__ sqv, const float* __restrict__ strength,
        float* __restrict__ out) {
    __shared__ __align__(16) unsigned short btile[3 * CN * DD]; // 48 KB, triple-buffered
    __shared__ unsigned int cand8[RM * 8];                      // 4 KB => 52 KB => 2 blocks/CU

    const int b = blockIdx.x;            // all 16 row-blocks of a batch share an XCD
    const int row0 = blockIdx.y * RM;
    const int tid = threadIdx.x;
    const int w = tid >> 6;
    const int lane = tid & 63;
    const int m = lane & 15;
    const int quad = lane >> 4;
    const float* __restrict__ xb = x + (size_t)b * NN * DD;
    const unsigned short* __restrict__ gb = PRE ? xb16g + (size_t)b * NN * DD : nullptr;

    // ---- A fragments direct from global: 2 row-groups x 4 k-chunks per lane ----
    short8 afrag[2][4];
    if constexpr (PRE) {
#pragma unroll
        for (int rg = 0; rg < 2; ++rg)
#pragma unroll
            for (int kc = 0; kc < 4; ++kc)
                afrag[rg][kc] = *reinterpret_cast<const short8*>(
                    gb + (size_t)(row0 + 32 * w + rg * 16 + m) * DD + kc * 32 + quad * 8);
    } else {
#pragma unroll
        for (int rg = 0; rg < 2; ++rg)
#pragma unroll
            for (int kc = 0; kc < 4; ++kc) {
                const float4* src = reinterpret_cast<const float4*>(
                    xb + (size_t)(row0 + 32 * w + rg * 16 + m) * DD + kc * 32 + quad * 8);
                float4 v0 = src[0], v1 = src[1];
                short8 pk;
                pk[0] = (short)f2bf(v0.x); pk[1] = (short)f2bf(v0.y);
                pk[2] = (short)f2bf(v0.z); pk[3] = (short)f2bf(v0.w);
                pk[4] = (short)f2bf(v1.x); pk[5] = (short)f2bf(v1.y);
                pk[6] = (short)f2bf(v1.z); pk[7] = (short)f2bf(v1.w);
                afrag[rg][kc] = pk;
            }
    }

    unsigned short* cur = btile;
    unsigned short* n1  = btile + CN * DD;
    unsigned short* n2  = btile + 2 * CN * DD;

    // ---- prologue: stage tiles 0 and 1; sq for tile 0; full drain once ----
    if constexpr (PRE) {
#pragma unroll
        for (int l = 0; l < 4; ++l) {
            int f = (l * 4 + w) * 64 + lane;
            int r = f >> 4, p = f & 15;
            int c = p ^ (r & 7);
            gl2lds16(gb + (size_t)r * DD + c * 8, cur + (l * 4 + w) * 512);
        }
#pragma unroll
        for (int l = 0; l < 4; ++l) {
            int f = (l * 4 + w) * 64 + lane;
            int r = f >> 4, p = f & 15;
            int c = p ^ (r & 7);
            gl2lds16(gb + (size_t)(CN + r) * DD + c * 8, n1 + (l * 4 + w) * 512);
        }
    } else {
#pragma unroll
        for (int l = 0; l < 8; ++l) {
            int id = l * 256 + tid;                 // tiles 0 and 1 = rows 0..127
            int r = id >> 4, c = id & 15, p = c ^ (r & 7);
            const float4* src = reinterpret_cast<const float4*>(xb + (size_t)r * DD + c * 8);
            float4 v0 = src[0], v1 = src[1];
            short8 pk;
            pk[0] = (short)f2bf(v0.x); pk[1] = (short)f2bf(v0.y);
            pk[2] = (short)f2bf(v0.z); pk[3] = (short)f2bf(v0.w);
            pk[4] = (short)f2bf(v1.x); pk[5] = (short)f2bf(v1.y);
            pk[6] = (short)f2bf(v1.z); pk[7] = (short)f2bf(v1.w);
            *reinterpret_cast<short8*>(btile + r * DD + p * 8) = pk;  // cur|n1 contiguous
        }
    }
    float sqb[4];
#pragma unroll
    for (int cc = 0; cc < 4; ++cc)
        sqb[cc] = sqv[(size_t)b * NN + cc * 16 + m] + 1024.0f;
    __syncthreads();   // one-time full drain: tiles 0,1 + sq ready

    // per-(lane, rg, reg) sorted top-4 packed keys (ascending).
    // Lossless: only 3 keys can be globally smaller than true rank-3, so it
    // can never be evicted from its lane-class top-4.
    unsigned int tk[2][4][4];
#pragma unroll
    for (int rg = 0; rg < 2; ++rg)
#pragma unroll
        for (int i = 0; i < 4; ++i)
#pragma unroll
            for (int q = 0; q < 4; ++q) tk[rg][i][q] = 0xFFFFFFFFu;

#pragma unroll 1
    for (int ct = 0; ct < NT; ++ct) {
        // ---- 1. prefetch sq for tile ct+1 (issued BEFORE the stage ops) ----
        float sqn[4];
        if (ct + 1 < NT) {
#pragma unroll
            for (int cc = 0; cc < 4; ++cc)
                sqn[cc] = sqv[(size_t)b * NN + (ct + 1) * CN + cc * 16 + m];
        }
        asm volatile("" ::: "memory");   // pin order: sqv loads precede stage issue

        // ---- 2. stage tile ct+2 into n2 (stays in flight across the barrier) ----
        if (ct + 2 < NT) {
            int cb = (ct + 2) * CN;
            if constexpr (PRE) {
#pragma unroll
                for (int l = 0; l < 4; ++l) {
                    int f = (l * 4 + w) * 64 + lane;
                    int r = f >> 4, p = f & 15;
                    int c = p ^ (r & 7);
                    gl2lds16(gb + (size_t)(cb + r) * DD + c * 8, n2 + (l * 4 + w) * 512);
                }
            } else {
#pragma unroll
                for (int l = 0; l < 4; ++l) {
                    int id = l * 256 + tid;
                    int r = id >> 4, c = id & 15, p = c ^ (r & 7);
                    const float4* src = reinterpret_cast<const float4*>(xb + (size_t)(cb + r) * DD + c * 8);
                    float4 v0 = src[0], v1 = src[1];
                    short8 pk;
                    pk[0] = (short)f2bf(v0.x); pk[1] = (short)f2bf(v0.y);
                    pk[2] = (short)f2bf(v0.z); pk[3] = (short)f2bf(v0.w);
                    pk[4] = (short)f2bf(v1.x); pk[5] = (short)f2bf(v1.y);
                    pk[6] = (short)f2bf(v1.z); pk[7] = (short)f2bf(v1.w);
                    *reinterpret_cast<short8*>(n2 + r * DD + p * 8) = pk;
                }
            }
        }

        // ---- 3. compute on cur: 32 MFMAs from 16 b128 reads (reuse=2) ----
        float4v acc[2][4];
#pragma unroll
        for (int rg = 0; rg < 2; ++rg)
#pragma unroll
            for (int cc = 0; cc < 4; ++cc) acc[rg][cc] = (float4v){0.f, 0.f, 0.f, 0.f};
#pragma unroll
        for (int kc = 0; kc < 4; ++kc) {
            short8 bfrag[4];
#pragma unroll
            for (int cc = 0; cc < 4; ++cc) {
                int rl = cc * 16 + m;
                int p = (kc * 4 + quad) ^ (m & 7);
                bfrag[cc] = *reinterpret_cast<const short8*>(cur + rl * DD + p * 8);
            }
#pragma unroll
            for (int rg = 0; rg < 2; ++rg)
#pragma unroll
                for (int cc = 0; cc < 4; ++cc)
                    acc[rg][cc] = __builtin_amdgcn_mfma_f32_16x16x32_bf16(
                        afrag[rg][kc], bfrag[cc], acc[rg][cc], 0, 0, 0);
        }

        // ---- 4. branchless selection: pack key, med3 sorted-insert into top-4 ----
#pragma unroll
        for (int cc = 0; cc < 4; ++cc) {
            unsigned int col = (unsigned int)(ct * CN + cc * 16 + m);
#pragma unroll
            for (int rg = 0; rg < 2; ++rg)
#pragma unroll
                for (int reg = 0; reg < 4; ++reg) {
                    float scb = fmaf(-2.f, acc[rg][cc][reg], sqb[cc]);   // 1024 + d2 - sqr > 0
                    unsigned int key = (__builtin_bit_cast(unsigned int, scb) & 0xFFFFF800u) | col;
                    unsigned int t0 = tk[rg][reg][0], t1 = tk[rg][reg][1];
                    unsigned int t2 = tk[rg][reg][2], t3 = tk[rg][reg][3];
                    tk[rg][reg][0] = umn(t0, key);
                    tk[rg][reg][1] = umed3(t0, t1, key);
                    tk[rg][reg][2] = umed3(t1, t2, key);
                    tk[rg][reg][3] = umed3(t2, t3, key);
                }
        }

        // ---- 5. roll sq (its wait retires stage(ct+1), leaves stage(ct+2) in flight) ----
        if (ct + 1 < NT) {
#pragma unroll
            for (int cc = 0; cc < 4; ++cc) sqb[cc] = sqn[cc] + 1024.0f;
        }

        // ---- 6. counted wait + barrier ----
        if constexpr (PRE) {
            if (ct + 2 < NT) {
                asm volatile("s_waitcnt vmcnt(4)" ::: "memory");  // stage(ct+1) landed
            } else {
                asm volatile("s_waitcnt vmcnt(0)" ::: "memory");  // tail drain
            }
            __builtin_amdgcn_s_barrier();
            __builtin_amdgcn_sched_barrier(0);
        } else {
            __syncthreads();
        }

        // ---- 7. rotate buffers ----
        unsigned short* t = cur; cur = n1; n1 = n2; n2 = t;
    }

    // ---- in-register merge: 16 lanes/quad-group x sorted-4 -> row top-8 ----
#pragma unroll
    for (int rg = 0; rg < 2; ++rg)
#pragma unroll
        for (int reg = 0; reg < 4; ++reg) {
            unsigned int e[8];
#pragma unroll
            for (int j = 0; j < 4; ++j) e[j] = tk[rg][reg][j];
#pragma unroll
            for (int j = 4; j < 8; ++j) e[j] = 0xFFFFFFFFu;
#pragma unroll
            for (int st = 0; st < 4; ++st) {
                int mask = 1 << st;
                unsigned int rv[8];
#pragma unroll
                for (int j = 0; j < 8; ++j)
                    rv[j] = (unsigned int)__shfl_xor((int)e[7 - j], mask, 64);
#pragma unroll
                for (int j = 0; j < 8; ++j) e[j] = umn(e[j], rv[j]);
                CSU(e[0], e[4]); CSU(e[1], e[5]); CSU(e[2], e[6]); CSU(e[3], e[7]);
                CSU(e[0], e[2]); CSU(e[1], e[3]); CSU(e[4], e[6]); CSU(e[5], e[7]);
                CSU(e[0], e[1]); CSU(e[2], e[3]); CSU(e[4], e[5]); CSU(e[6], e[7]);
            }
            if (m == 0) {
                int row = 32 * w + rg * 16 + quad * 4 + reg;
#pragma unroll
                for (int j = 0; j < 8; ++j) cand8[row * 8 + j] = e[j];
            }
        }
    __syncthreads();

    // alias btile for refine scratch (all tile reads done)
    double* refd = reinterpret_cast<double*>(btile);           // 8 KB
    int* best3 = reinterpret_cast<int*>(btile) + 2048;         // next 1.5 KB

    // ---- refine: exact fp64 distance; 2 threads/row x 4 candidates ----
    {
        int r = tid >> 1, h = tid & 1;
        int grow = row0 + r;
        int ci[4];
#pragma unroll
        for (int j = 0; j < 4; ++j) ci[j] = (int)(cand8[r * 8 + h * 4 + j] & 0x7FFu);
        const float* pr = xb + (size_t)grow * DD;
        const float* pc[4];
#pragma unroll
        for (int j = 0; j < 4; ++j) pc[j] = xb + (size_t)ci[j] * DD;
        double a[4] = {0.0, 0.0, 0.0, 0.0};
#pragma unroll 4
        for (int d4 = 0; d4 < 32; ++d4) {
            float4 wv = *reinterpret_cast<const float4*>(pr + d4 * 4);
#pragma unroll
            for (int j = 0; j < 4; ++j) {
                float4 v = *reinterpret_cast<const float4*>(pc[j] + d4 * 4);
                double d;
                d = (double)wv.x - (double)v.x; a[j] += d * d;
                d = (double)wv.y - (double)v.y; a[j] += d * d;
                d = (double)wv.z - (double)v.z; a[j] += d * d;
                d = (double)wv.w - (double)v.w; a[j] += d * d;
            }
        }
#pragma unroll
        for (int j = 0; j < 4; ++j)
            refd[r * 8 + h * 4 + j] = (ci[j] == grow) ? DBL_MAX : a[j];
    }
    __syncthreads();

    // ---- final top-3 by (exact d2, idx) ----
    if (tid < RM) {
        int r = tid;
        double b0 = DBL_MAX, b1 = DBL_MAX, b2 = DBL_MAX;
        int i0 = 0x7fffffff, i1 = 0x7fffffff, i2 = 0x7fffffff;
        for (int e = 0; e < 8; ++e) {
            double dv = refd[r * 8 + e];
            int ix = (int)(cand8[r * 8 + e] & 0x7FFu);
            if (dv < b2 || (dv == b2 && ix < i2)) {
                b2 = dv; i2 = ix;
                if (b1 > b2 || (b1 == b2 && i1 > i2)) { double td = b1; b1 = b2; b2 = td; int tn = i1; i1 = i2; i2 = tn; }
                if (b0 > b1 || (b0 == b1 && i0 > i1)) { double td = b0; b0 = b1; b1 = td; int tn = i0; i0 = i1; i1 = tn; }
            }
        }
        best3[r * 3 + 0] = i0; best3[r * 3 + 1] = i1; best3[r * 3 + 2] = i2;
    }
    __syncthreads();

    // ---- output: 2 threads/row x 64 floats ----
    {
        int r = tid >> 1, q = tid & 1;
        float s = fminf(fmaxf(strength[0], 0.f), 1.f);
        const float* pa = xb + (size_t)(row0 + r) * DD + q * 64;
        const float* p1 = xb + (size_t)best3[r * 3 + 0] * DD + q * 64;
        const float* p2 = xb + (size_t)best3[r * 3 + 1] * DD + q * 64;
        const float* p3 = xb + (size_t)best3[r * 3 + 2] * DD + q * 64;
        float* po = out + ((size_t)b * NN + row0 + r) * DD + q * 64;
#pragma unroll
        for (int l = 0; l < 16; ++l) {
            float4 a  = *reinterpret_cast<const float4*>(pa + l * 4);
            float4 v1 = *reinterpret_cast<const float4*>(p1 + l * 4);
            float4 v2 = *reinterpret_cast<const float4*>(p2 + l * 4);
            float4 v3 = *reinterpret_cast<const float4*>(p3 + l * 4);
            float4 o;
            o.x = (1.f - s) * a.x + s * ((v1.x + v2.x + v3.x) / 3.f);
            o.y = (1.f - s) * a.y + s * ((v1.y + v2.y + v3.y) / 3.f);
            o.z = (1.f - s) * a.z + s * ((v1.z + v2.z + v3.z) / 3.f);
            o.w = (1.f - s) * a.w + s * ((v1.w + v2.w + v3.w) / 3.f);
            *reinterpret_cast<float4*>(po + l * 4) = o;
        }
    }
}

extern "C" void kernel_launch(void* const* d_in, const int* in_sizes, int n_in,
                              void* d_out, int out_size, void* d_ws, size_t ws_size,
                              hipStream_t stream) {
    const float* x = (const float*)d_in[0];
    const float* strength = (const float*)d_in[1];
    float* out = (float*)d_out;
    float* sq = (float*)d_ws;
    unsigned short* xb16 = (unsigned short*)((char*)d_ws + 256 * 1024);
    const size_t need = 256 * 1024 + (size_t)BB * NN * DD * sizeof(unsigned short);

    if (ws_size >= need) {
        prep_kernel<<<dim3((BB * NN * DD / 4) / 256), 256, 0, stream>>>(x, xb16, sq);
        knn_kernel<true><<<dim3(BB, NN / RM), 256, 0, stream>>>(x, xb16, sq, strength, out);
    } else {
        sq_kernel<<<dim3((BB * NN * 4) / 256), 256, 0, stream>>>(x, sq);
        knn_kernel<false><<<dim3(BB, NN / RM), 256, 0, stream>>>(x, nullptr, sq, strength, out);
    }
}